// Round 6
// baseline (193.429 us; speedup 1.0000x reference)
//
#include <hip/hip_runtime.h>
#include <hip/hip_fp16.h>

// B=32768, D=128, L=3, R=64, O=64. fp32 in/out, f16 MFMA compute.
// Round-3 LDS-ring structure + counted-vmcnt 3-slot ring (1 chunk in flight
// across every barrier), T-buffer eliminated (tp/stage-D read the swizzled
// f32 reduce-scratch directly), xn12 XOR-swizzled (conflict-free write+read).
// x read exactly once; core chunk LDS reads are read-once (M-unroll-2).
typedef _Float16 f16x8 __attribute__((ext_vector_type(8)));
typedef float f32x16 __attribute__((ext_vector_type(16)));

union H2x4 { f16x8 v; __half2 h2[4]; unsigned u[4]; };
union U1H2 { unsigned u; __half2 h; };

#define TB 64               // batch rows per workgroup (512 WGs = 2/CU)
// LDS layout (bytes)
#define SCR_OFF  32768      // ring slot 2 doubles as f32 scr [64][64] col-swz
#define XN12_OFF 49152      // xn slices 1,2: [d<128] 256B rows, XOR-swz, 32KB
#define SMEM_BYTES 81920    // 2 WGs/CU: 2 x 81920 = 163840 = full LDS
// workspace layout (bytes)
#define WS_CT1   0          // core1 -> [d][s][r] f16, swizzled, 1MB
#define WS_CT2   1048576    // core2 same
#define WS_L0T   2097152    // layer0^T [r][d] f16, 16KB
#define WS_LASTT 2113536    // last^T [o][r] f16, 8KB

#define WAITBAR2() asm volatile("s_waitcnt vmcnt(2)\n\ts_barrier" ::: "memory")
#define WAITBAR0() asm volatile("s_waitcnt vmcnt(0)\n\ts_barrier" ::: "memory")

__device__ __forceinline__ void gload_lds16(const void* g, void* l) {
  __builtin_amdgcn_global_load_lds(
      (const __attribute__((address_space(1))) unsigned int*)g,
      (__attribute__((address_space(3))) unsigned int*)l, 16, 0, 0);
}

// stage one 16KB core chunk (2 d's): 2 loads/thread
__device__ __forceinline__ void issue_chunk16(const unsigned char* g,
                                              unsigned char* l, int tid) {
  gload_lds16(g + tid * 16, l + tid * 16);
  gload_lds16(g + tid * 16 + 8192, l + tid * 16 + 8192);
}

__device__ __forceinline__ unsigned pack_h2(float a, float b) {
  return (unsigned)__half_as_ushort(__float2half(a)) |
         ((unsigned)__half_as_ushort(__float2half(b)) << 16);
}

// 4-way (p x kh) cross-wave reduce into swizzled f32 scr (ring slot 2).
// Accumulators passed BY VALUE (regs). scr[row][col ^ ((row&7)<<2)].
__device__ __forceinline__ void reduce_T(unsigned char* smem, f32x16 a0, f32x16 a1,
                                         int p, int kh, int h, int scol) {
  float* scr = (float*)(smem + SCR_OFF);
  __syncthreads();
  if ((p | kh) == 0) {                    // group (0,0) plain-writes
#pragma unroll
    for (int j = 0; j < 16; ++j) {
      const int r0 = (j & 3) + 8 * (j >> 2) + 4 * h;
      const int cs = scol ^ ((r0 & 7) << 2);   // (32+r0)&7 == r0&7
      scr[r0 * 64 + cs] = a0[j];
      scr[(32 + r0) * 64 + cs] = a1[j];
    }
  }
  __syncthreads();
  if ((p | kh) != 0) {                    // other 3 groups atomic-add
#pragma unroll
    for (int j = 0; j < 16; ++j) {
      const int r0 = (j & 3) + 8 * (j >> 2) + 4 * h;
      const int cs = scol ^ ((r0 & 7) << 2);
      atomicAdd(&scr[r0 * 64 + cs], a0[j]);
      atomicAdd(&scr[(32 + r0) * 64 + cs], a1[j]);
    }
  }
  __syncthreads();
}

// read one f16x8 A-fragment (8 consecutive r-cols at c0) from swizzled scr
__device__ __forceinline__ f16x8 scr_frag(const float* scr, int row, int c0) {
  const int sw = (row & 7) << 2;
  const float4 w0 = *(const float4*)(scr + row * 64 + (c0 ^ sw));
  const float4 w1 = *(const float4*)(scr + row * 64 + ((c0 + 4) ^ sw));
  H2x4 t;
  t.u[0] = pack_h2(w0.x, w0.y);
  t.u[1] = pack_h2(w0.z, w0.w);
  t.u[2] = pack_h2(w1.x, w1.y);
  t.u[3] = pack_h2(w1.z, w1.w);
  return t.v;
}

// ---- prep: cast weights to f16 in the layouts the main kernel wants ----
__global__ void __launch_bounds__(512) tt_prep(
    const float* __restrict__ layer0, const float* __restrict__ core1,
    const float* __restrict__ core2, const float* __restrict__ last,
    unsigned char* __restrict__ ws) {
  const int tid = blockIdx.x * 512 + threadIdx.x;
  if (tid < 524288) {                       // ct1/ct2: 2 x 262144 words
    const int which = tid >> 18;
    const int w = tid & 262143;
    const float* core = which ? core2 : core1;
    unsigned char* ct = ws + (which ? WS_CT2 : WS_CT1);
    const int d = w >> 11, rem = w & 2047, s = rem >> 5, j = rem & 31, r = 2 * j;
    const unsigned val = pack_h2(core[r * 8192 + d * 64 + s],
                                 core[(r + 1) * 8192 + d * 64 + s]);
    // byte (2r) within the [s][r] plane XOR-swizzled by ((s&7)<<4)
    *(unsigned*)(ct + d * 8192 + s * 128 + 4 * (j ^ ((s & 7) << 2))) = val;
  } else if (tid < 528384) {                // l0t: 4096 words, [r][d] f16 (256B rows)
    const int w = tid - 524288;
    const int r = w >> 6, j = w & 63, d = 2 * j;
    const unsigned val = pack_h2(layer0[d * 64 + r], layer0[(d + 1) * 64 + r]);
    *(unsigned*)(ws + WS_L0T + r * 256 + 4 * j) = val;
  } else if (tid < 530432) {                // lastT: 2048 words, [o][r] f16 (128B rows)
    const int w = tid - 528384;
    const int o = w >> 5, j = w & 31, r = 2 * j;
    const unsigned val = pack_h2(last[r * 64 + o], last[(r + 1) * 64 + o]);
    *(unsigned*)(ws + WS_LASTT + o * 128 + 4 * j) = val;
  }
}

// ---- fused main kernel: LN + 4-stage tensor-train chain ----
__global__ void __launch_bounds__(512, 4) tt_fused(
    const float* __restrict__ x, const float* __restrict__ lnw,
    const float* __restrict__ lnb, const unsigned char* __restrict__ ws,
    float* __restrict__ out) {
  __shared__ alignas(16) unsigned char smem[SMEM_BYTES];
  const int tid = threadIdx.x;
  const int wid = tid >> 6;
  const int lane = tid & 63;
  const int l31 = lane & 31;
  const int h = lane >> 5;
  const int p  = wid & 1;           // d-parity within chunk
  const int kh = (wid >> 1) & 1;    // r-half (K-split over r)
  const int sb = (wid >> 2) & 1;    // s-block (32 cols)
  const int bg0 = blockIdx.x * TB;
  const int scol = sb * 32 + l31;   // this lane's B-col
  const int sOff = scol * 128;
  const int swzA = (l31 & 7) << 4;  // == (row&7)<<4 for row = mb*32+l31

  // ---------- phase 0: LN; xn0 -> slot0 [row][256B swz]; xn1,2 -> XN12 swz ----------
  {
    float wv[6], bv[6];
#pragma unroll
    for (int k = 0; k < 6; ++k) { wv[k] = lnw[lane + 64 * k]; bv[k] = lnb[lane + 64 * k]; }
#pragma unroll
    for (int rr = 0; rr < 8; ++rr) {
      const int row = wid * 8 + rr;
      const float* xrow = x + (size_t)(bg0 + row) * 384;
      float v[6];
#pragma unroll
      for (int k = 0; k < 6; ++k) v[k] = xrow[lane + 64 * k];
      float s = 0.f, ss = 0.f;
#pragma unroll
      for (int k = 0; k < 6; ++k) { s += v[k]; ss += v[k] * v[k]; }
#pragma unroll
      for (int m = 1; m < 64; m <<= 1) { s += __shfl_xor(s, m); ss += __shfl_xor(ss, m); }
      const float mu = s * (1.f / 384.f);
      const float var = ss * (1.f / 384.f) - mu * mu;
      const float rstd = rsqrtf(var + 1e-5f);
#pragma unroll
      for (int k = 0; k < 6; ++k) {
        const int i = lane + 64 * k;        // i = 3*d + sl
        const int d = i / 3;
        const int sl = i - 3 * d;
        const float xv = (v[k] - mu) * rstd * wv[k] + bv[k];
        if (sl == 0) {
          *(__half*)(smem + row * 256 + ((2 * d) ^ ((row & 7) << 4))) =
              __float2half(xv);
        } else {
          *(__half*)(smem + XN12_OFF + d * 256 + ((4 * row) ^ ((d & 15) << 3)) +
                     2 * (sl - 1)) = __float2half(xv);
        }
      }
    }
  }
  __syncthreads();

  f32x16 acc0, acc1;  // rows 0..31 / 32..63 of this wave's (kh,sb) partial

  // ---------- stage A: T1 = xn0 @ layer0 (K=128, 4-way (p,kh) K-split) ----------
#pragma unroll
  for (int i = 0; i < 16; ++i) { acc0[i] = 0.f; acc1[i] = 0.f; }
  {
    const unsigned char* l0t = ws + WS_L0T;
#pragma unroll
    for (int kbL = 0; kbL < 2; ++kbL) {
      const int cb = (((p << 1) | kh) * 2 + kbL) * 32 + h * 16;
      f16x8 bf = *(const f16x8*)(l0t + scol * 256 + cb);
      f16x8 a0 = *(const f16x8*)(smem + l31 * 256 + (cb ^ swzA));
      f16x8 a1 = *(const f16x8*)(smem + (32 + l31) * 256 + (cb ^ swzA));
      acc0 = __builtin_amdgcn_mfma_f32_32x32x16_f16(a0, bf, acc0, 0, 0, 0);
      acc1 = __builtin_amdgcn_mfma_f32_32x32x16_f16(a1, bf, acc1, 0, 0, 0);
    }
  }
  reduce_T(smem, acc0, acc1, p, kh, h, scol);  // -> scr (slot2; xn0/slot0 dead)

  // ---------- stages B,C: T = KR(T, xn_l) @ core_l ----------
  for (int st = 0; st < 2; ++st) {
    const unsigned char* ctg = ws + (st ? WS_CT2 : WS_CT1);
    const float* scr = (const float*)(smem + SCR_OFF);

    // prologue: chunk 0 -> slot 0 (slot0's prior readers done at reduce_T sync)
    issue_chunk16(ctg, smem, tid);

    // T rows (both m-blocks x this wave's r-half K=32) from scr into regs
    const int c0 = kh * 32 + h * 8;
    f16x8 tpv00 = scr_frag(scr, l31, c0);
    f16x8 tpv01 = scr_frag(scr, l31, c0 + 16);
    f16x8 tpv10 = scr_frag(scr, 32 + l31, c0);
    f16x8 tpv11 = scr_frag(scr, 32 + l31, c0 + 16);
    H2x4 tp00, tp01, tp10, tp11;
    tp00.v = tpv00; tp01.v = tpv01; tp10.v = tpv10; tp11.v = tpv11;
    __syncthreads();  // all tp reads done before slot2 (scr) rejoins the ring

#pragma unroll
    for (int i = 0; i < 16; ++i) { acc0[i] = 0.f; acc1[i] = 0.f; }

    int cur = 0;  // ring slot of chunk cg (wave-uniform)
#pragma unroll 1
    for (int cg = 0; cg < 64; ++cg) {
      const int nb = (cur == 2) ? 0 : cur + 1;
      if (cg < 63) {
        // slot nb held chunk cg-2; its readers passed iter cg-1's barrier.
        issue_chunk16(ctg + (cg + 1) * 16384, smem + nb * 16384, tid);
        WAITBAR2();   // drain chunk cg's 2 loads; cg+1's stay in flight
      } else {
        WAITBAR0();
      }
      // compute chunk cg: this wave's d = 2*cg + p
      const unsigned char* bp = smem + cur * 16384 + p * 8192 + sOff;
      const int d = 2 * cg + p;
      const unsigned char* xp = smem + XN12_OFF + d * 256 +
                                ((4 * l31) ^ ((d & 15) << 3)) + 2 * st;
      const unsigned xv0 = *(const unsigned short*)xp;
      const unsigned xv1 = *(const unsigned short*)(xp + 128);
      U1H2 d0, d1;
      d0.u = xv0 | (xv0 << 16);
      d1.u = xv1 | (xv1 << 16);
      const int rb = kh * 64 + h * 16;
      {  // kbL = 0
        f16x8 bf = *(const f16x8*)(bp + (rb ^ swzA));
        H2x4 af0, af1;
#pragma unroll
        for (int i = 0; i < 4; ++i) {
          af0.h2[i] = __hmul2(tp00.h2[i], d0.h);
          af1.h2[i] = __hmul2(tp10.h2[i], d1.h);
        }
        acc0 = __builtin_amdgcn_mfma_f32_32x32x16_f16(af0.v, bf, acc0, 0, 0, 0);
        acc1 = __builtin_amdgcn_mfma_f32_32x32x16_f16(af1.v, bf, acc1, 0, 0, 0);
      }
      {  // kbL = 1
        f16x8 bf = *(const f16x8*)(bp + ((rb + 32) ^ swzA));
        H2x4 af0, af1;
#pragma unroll
        for (int i = 0; i < 4; ++i) {
          af0.h2[i] = __hmul2(tp01.h2[i], d0.h);
          af1.h2[i] = __hmul2(tp11.h2[i], d1.h);
        }
        acc0 = __builtin_amdgcn_mfma_f32_32x32x16_f16(af0.v, bf, acc0, 0, 0, 0);
        acc1 = __builtin_amdgcn_mfma_f32_32x32x16_f16(af1.v, bf, acc1, 0, 0, 0);
      }
      cur = nb;
    }
    reduce_T(smem, acc0, acc1, p, kh, h, scol);  // -> scr again (T2 then T3)
  }

  // ---------- stage D: out = T3 @ last (p==0 waves; rows kh*32..) ----------
  if (p == 0) {
    const float* scr = (const float*)(smem + SCR_OFF);
    f32x16 accd;
#pragma unroll
    for (int i = 0; i < 16; ++i) accd[i] = 0.f;
    const unsigned char* lastT = ws + WS_LASTT;
#pragma unroll
    for (int kb = 0; kb < 4; ++kb) {
      const int cb = kb * 32 + h * 16;
      f16x8 bf = *(const f16x8*)(lastT + scol * 128 + cb);
      f16x8 af = scr_frag(scr, kh * 32 + l31, kb * 16 + h * 8);
      accd = __builtin_amdgcn_mfma_f32_32x32x16_f16(af, bf, accd, 0, 0, 0);
    }
#pragma unroll
    for (int j = 0; j < 16; ++j) {
      const int r0 = (j & 3) + 8 * (j >> 2) + 4 * h;
      out[(size_t)(bg0 + kh * 32 + r0) * 64 + scol] = accd[j];
    }
  }
}

extern "C" void kernel_launch(void* const* d_in, const int* in_sizes, int n_in,
                              void* d_out, int out_size, void* d_ws, size_t ws_size,
                              hipStream_t stream) {
  const float* x      = (const float*)d_in[0];
  const float* layer0 = (const float*)d_in[1];
  const float* core1  = (const float*)d_in[2];
  const float* core2  = (const float*)d_in[3];
  const float* last   = (const float*)d_in[4];
  const float* lnw    = (const float*)d_in[5];
  const float* lnb    = (const float*)d_in[6];
  unsigned char* ws   = (unsigned char*)d_ws;
  float* outp         = (float*)d_out;

  tt_prep<<<1036, 512, 0, stream>>>(layer0, core1, core2, last, ws);
  tt_fused<<<512, 512, 0, stream>>>(x, lnw, lnb, ws, outp);
}

// Round 7
// 190.787 us; speedup vs baseline: 1.0138x; 1.0138x over previous
//
#include <hip/hip_runtime.h>
#include <hip/hip_fp16.h>

// B=32768, D=128, L=3, R=64, O=64. fp32 in/out, f16 MFMA compute.
// Round-3 proven 2-slot drain-0 ring schedule + round-6 T-elimination.
// LDS cut to 65536B (2 WGs/CU with 32KB slack; 81920 hit the 160KiB cliff
// -> 1 WG/CU -> 1.83x slowdown in r6). slot0 = xn0 / stage-A A-frags / f32
// reduce scratch (barrier-separated); ring = slot1,slot0 alternating so the
// prologue DMA overlaps tp reads. x read exactly once; core chunk LDS reads
// read-once (M-unroll-2, p/kh/sb wave split).
typedef _Float16 f16x8 __attribute__((ext_vector_type(8)));
typedef float f32x16 __attribute__((ext_vector_type(16)));

union H2x4 { f16x8 v; __half2 h2[4]; unsigned u[4]; };
union U1H2 { unsigned u; __half2 h; };

#define TB 64               // batch rows per workgroup (512 WGs = 2/CU)
// LDS layout (bytes)
#define SCR_OFF  0          // slot0: xn0 (16KB) -> f32 scr [64][64] col-swz
#define XN12_OFF 32768      // xn slices 1,2: [d<128] 256B rows, XOR-swz, 32KB
#define SMEM_BYTES 65536    // 2 WGs/CU: 131072 <= 163840 (32KB slack)
// workspace layout (bytes)
#define WS_CT1   0          // core1 -> [d][s][r] f16, swizzled, 1MB
#define WS_CT2   1048576    // core2 same
#define WS_L0T   2097152    // layer0^T [r][d] f16, 16KB
#define WS_LASTT 2113536    // last^T [o][r] f16, 8KB

#define WAITBAR0() asm volatile("s_waitcnt vmcnt(0)\n\ts_barrier" ::: "memory")

__device__ __forceinline__ void gload_lds16(const void* g, void* l) {
  __builtin_amdgcn_global_load_lds(
      (const __attribute__((address_space(1))) unsigned int*)g,
      (__attribute__((address_space(3))) unsigned int*)l, 16, 0, 0);
}

// stage one 16KB core chunk (2 d's): 2 loads/thread
__device__ __forceinline__ void issue_chunk16(const unsigned char* g,
                                              unsigned char* l, int tid) {
  gload_lds16(g + tid * 16, l + tid * 16);
  gload_lds16(g + tid * 16 + 8192, l + tid * 16 + 8192);
}

__device__ __forceinline__ unsigned pack_h2(float a, float b) {
  return (unsigned)__half_as_ushort(__float2half(a)) |
         ((unsigned)__half_as_ushort(__float2half(b)) << 16);
}

// 4-way (p x kh) cross-wave reduce into swizzled f32 scr (slot0).
// Accumulators passed BY VALUE (regs). scr[row][col ^ ((row&7)<<2)].
__device__ __forceinline__ void reduce_T(unsigned char* smem, f32x16 a0, f32x16 a1,
                                         int p, int kh, int h, int scol) {
  float* scr = (float*)(smem + SCR_OFF);
  __syncthreads();
  if ((p | kh) == 0) {                    // group (0,0) plain-writes
#pragma unroll
    for (int j = 0; j < 16; ++j) {
      const int r0 = (j & 3) + 8 * (j >> 2) + 4 * h;
      const int cs = scol ^ ((r0 & 7) << 2);   // (32+r0)&7 == r0&7
      scr[r0 * 64 + cs] = a0[j];
      scr[(32 + r0) * 64 + cs] = a1[j];
    }
  }
  __syncthreads();
  if ((p | kh) != 0) {                    // other 3 groups atomic-add
#pragma unroll
    for (int j = 0; j < 16; ++j) {
      const int r0 = (j & 3) + 8 * (j >> 2) + 4 * h;
      const int cs = scol ^ ((r0 & 7) << 2);
      atomicAdd(&scr[r0 * 64 + cs], a0[j]);
      atomicAdd(&scr[(32 + r0) * 64 + cs], a1[j]);
    }
  }
  __syncthreads();
}

// read one f16x8 A-fragment (8 consecutive r-cols at c0) from swizzled scr
__device__ __forceinline__ f16x8 scr_frag(const float* scr, int row, int c0) {
  const int sw = (row & 7) << 2;
  const float4 w0 = *(const float4*)(scr + row * 64 + (c0 ^ sw));
  const float4 w1 = *(const float4*)(scr + row * 64 + ((c0 + 4) ^ sw));
  H2x4 t;
  t.u[0] = pack_h2(w0.x, w0.y);
  t.u[1] = pack_h2(w0.z, w0.w);
  t.u[2] = pack_h2(w1.x, w1.y);
  t.u[3] = pack_h2(w1.z, w1.w);
  return t.v;
}

// ---- prep: cast weights to f16 in the layouts the main kernel wants ----
__global__ void __launch_bounds__(512) tt_prep(
    const float* __restrict__ layer0, const float* __restrict__ core1,
    const float* __restrict__ core2, const float* __restrict__ last,
    unsigned char* __restrict__ ws) {
  const int tid = blockIdx.x * 512 + threadIdx.x;
  if (tid < 524288) {                       // ct1/ct2: 2 x 262144 words
    const int which = tid >> 18;
    const int w = tid & 262143;
    const float* core = which ? core2 : core1;
    unsigned char* ct = ws + (which ? WS_CT2 : WS_CT1);
    const int d = w >> 11, rem = w & 2047, s = rem >> 5, j = rem & 31, r = 2 * j;
    const unsigned val = pack_h2(core[r * 8192 + d * 64 + s],
                                 core[(r + 1) * 8192 + d * 64 + s]);
    // byte (2r) within the [s][r] plane XOR-swizzled by ((s&7)<<4)
    *(unsigned*)(ct + d * 8192 + s * 128 + 4 * (j ^ ((s & 7) << 2))) = val;
  } else if (tid < 528384) {                // l0t: 4096 words, [r][d] f16 (256B rows)
    const int w = tid - 524288;
    const int r = w >> 6, j = w & 63, d = 2 * j;
    const unsigned val = pack_h2(layer0[d * 64 + r], layer0[(d + 1) * 64 + r]);
    *(unsigned*)(ws + WS_L0T + r * 256 + 4 * j) = val;
  } else if (tid < 530432) {                // lastT: 2048 words, [o][r] f16 (128B rows)
    const int w = tid - 528384;
    const int o = w >> 5, j = w & 31, r = 2 * j;
    const unsigned val = pack_h2(last[r * 64 + o], last[(r + 1) * 64 + o]);
    *(unsigned*)(ws + WS_LASTT + o * 128 + 4 * j) = val;
  }
}

// ---- fused main kernel: LN + 4-stage tensor-train chain ----
__global__ void __launch_bounds__(512, 4) tt_fused(
    const float* __restrict__ x, const float* __restrict__ lnw,
    const float* __restrict__ lnb, const unsigned char* __restrict__ ws,
    float* __restrict__ out) {
  __shared__ alignas(16) unsigned char smem[SMEM_BYTES];
  const int tid = threadIdx.x;
  const int wid = tid >> 6;
  const int lane = tid & 63;
  const int l31 = lane & 31;
  const int h = lane >> 5;
  const int p  = wid & 1;           // d-parity within chunk
  const int kh = (wid >> 1) & 1;    // r-half (K-split over r)
  const int sb = (wid >> 2) & 1;    // s-block (32 cols)
  const int bg0 = blockIdx.x * TB;
  const int scol = sb * 32 + l31;   // this lane's B-col
  const int sOff = scol * 128;
  const int swzA = (l31 & 7) << 4;  // == (row&7)<<4 for row = mb*32+l31

  // ---------- phase 0: LN; xn0 -> slot0 [row][256B swz]; xn1,2 -> XN12 swz ----------
  {
    float wv[6], bv[6];
#pragma unroll
    for (int k = 0; k < 6; ++k) { wv[k] = lnw[lane + 64 * k]; bv[k] = lnb[lane + 64 * k]; }
#pragma unroll
    for (int rr = 0; rr < 8; ++rr) {
      const int row = wid * 8 + rr;
      const float* xrow = x + (size_t)(bg0 + row) * 384;
      float v[6];
#pragma unroll
      for (int k = 0; k < 6; ++k) v[k] = xrow[lane + 64 * k];
      float s = 0.f, ss = 0.f;
#pragma unroll
      for (int k = 0; k < 6; ++k) { s += v[k]; ss += v[k] * v[k]; }
#pragma unroll
      for (int m = 1; m < 64; m <<= 1) { s += __shfl_xor(s, m); ss += __shfl_xor(ss, m); }
      const float mu = s * (1.f / 384.f);
      const float var = ss * (1.f / 384.f) - mu * mu;
      const float rstd = rsqrtf(var + 1e-5f);
#pragma unroll
      for (int k = 0; k < 6; ++k) {
        const int i = lane + 64 * k;        // i = 3*d + sl
        const int d = i / 3;
        const int sl = i - 3 * d;
        const float xv = (v[k] - mu) * rstd * wv[k] + bv[k];
        if (sl == 0) {
          *(__half*)(smem + row * 256 + ((2 * d) ^ ((row & 7) << 4))) =
              __float2half(xv);
        } else {
          *(__half*)(smem + XN12_OFF + d * 256 + ((4 * row) ^ ((d & 15) << 3)) +
                     2 * (sl - 1)) = __float2half(xv);
        }
      }
    }
  }
  __syncthreads();

  f32x16 acc0, acc1;  // rows 0..31 / 32..63 of this wave's (kh,sb) partial

  // ---------- stage A: T1 = xn0 @ layer0 (K=128, 4-way (p,kh) K-split) ----------
#pragma unroll
  for (int i = 0; i < 16; ++i) { acc0[i] = 0.f; acc1[i] = 0.f; }
  {
    const unsigned char* l0t = ws + WS_L0T;
#pragma unroll
    for (int kbL = 0; kbL < 2; ++kbL) {
      const int cb = (((p << 1) | kh) * 2 + kbL) * 32 + h * 16;
      f16x8 bf = *(const f16x8*)(l0t + scol * 256 + cb);
      f16x8 a0 = *(const f16x8*)(smem + l31 * 256 + (cb ^ swzA));
      f16x8 a1 = *(const f16x8*)(smem + (32 + l31) * 256 + (cb ^ swzA));
      acc0 = __builtin_amdgcn_mfma_f32_32x32x16_f16(a0, bf, acc0, 0, 0, 0);
      acc1 = __builtin_amdgcn_mfma_f32_32x32x16_f16(a1, bf, acc1, 0, 0, 0);
    }
  }
  reduce_T(smem, acc0, acc1, p, kh, h, scol);  // -> scr in slot0 (xn0 dead)

  // ---------- stages B,C: T = KR(T, xn_l) @ core_l ----------
  for (int st = 0; st < 2; ++st) {
    const unsigned char* ctg = ws + (st ? WS_CT2 : WS_CT1);
    const float* scr = (const float*)(smem + SCR_OFF);

    // prologue: chunk 0 -> slot1 (slot0 = scr still live for tp reads)
    issue_chunk16(ctg, smem + 16384, tid);

    // T rows (both m-blocks x this wave's r-half K=32) from scr into regs
    const int c0 = kh * 32 + h * 8;
    f16x8 tpv00 = scr_frag(scr, l31, c0);
    f16x8 tpv01 = scr_frag(scr, l31, c0 + 16);
    f16x8 tpv10 = scr_frag(scr, 32 + l31, c0);
    f16x8 tpv11 = scr_frag(scr, 32 + l31, c0 + 16);
    H2x4 tp00, tp01, tp10, tp11;
    tp00.v = tpv00; tp01.v = tpv01; tp10.v = tpv10; tp11.v = tpv11;
    __syncthreads();  // all tp reads retired before slot0 rejoins the ring

#pragma unroll
    for (int i = 0; i < 16; ++i) { acc0[i] = 0.f; acc1[i] = 0.f; }

    // ring: chunk cg lives in slot ((cg&1)^1): c0->slot1, c1->slot0, ...
#pragma unroll 1
    for (int cg = 0; cg < 64; ++cg) {
      WAITBAR0();   // chunk cg landed (issued >= 1 full iteration ago)
      if (cg < 63)  // issue cg+1 into the slot all waves just finished reading
        issue_chunk16(ctg + (cg + 1) * 16384, smem + (cg & 1) * 16384, tid);
      // compute chunk cg: this wave's d = 2*cg + p
      const unsigned char* bp = smem + ((cg & 1) ^ 1) * 16384 + p * 8192 + sOff;
      const int d = 2 * cg + p;
      const unsigned char* xp = smem + XN12_OFF + d * 256 +
                                ((4 * l31) ^ ((d & 15) << 3)) + 2 * st;
      const unsigned xv0 = *(const unsigned short*)xp;
      const unsigned xv1 = *(const unsigned short*)(xp + 128);
      U1H2 d0, d1;
      d0.u = xv0 | (xv0 << 16);
      d1.u = xv1 | (xv1 << 16);
      const int rb = kh * 64 + h * 16;
      {  // kbL = 0
        f16x8 bf = *(const f16x8*)(bp + (rb ^ swzA));
        H2x4 af0, af1;
#pragma unroll
        for (int i = 0; i < 4; ++i) {
          af0.h2[i] = __hmul2(tp00.h2[i], d0.h);
          af1.h2[i] = __hmul2(tp10.h2[i], d1.h);
        }
        acc0 = __builtin_amdgcn_mfma_f32_32x32x16_f16(af0.v, bf, acc0, 0, 0, 0);
        acc1 = __builtin_amdgcn_mfma_f32_32x32x16_f16(af1.v, bf, acc1, 0, 0, 0);
      }
      {  // kbL = 1
        f16x8 bf = *(const f16x8*)(bp + ((rb + 32) ^ swzA));
        H2x4 af0, af1;
#pragma unroll
        for (int i = 0; i < 4; ++i) {
          af0.h2[i] = __hmul2(tp01.h2[i], d0.h);
          af1.h2[i] = __hmul2(tp11.h2[i], d1.h);
        }
        acc0 = __builtin_amdgcn_mfma_f32_32x32x16_f16(af0.v, bf, acc0, 0, 0, 0);
        acc1 = __builtin_amdgcn_mfma_f32_32x32x16_f16(af1.v, bf, acc1, 0, 0, 0);
      }
    }
    reduce_T(smem, acc0, acc1, p, kh, h, scol);  // -> scr again (T2 then T3)
  }

  // ---------- stage D: out = T3 @ last (p==0 waves; rows kh*32..) ----------
  if (p == 0) {
    const float* scr = (const float*)(smem + SCR_OFF);
    f32x16 accd;
#pragma unroll
    for (int i = 0; i < 16; ++i) accd[i] = 0.f;
    const unsigned char* lastT = ws + WS_LASTT;
#pragma unroll
    for (int kb = 0; kb < 4; ++kb) {
      const int cb = kb * 32 + h * 16;
      f16x8 bf = *(const f16x8*)(lastT + scol * 128 + cb);
      f16x8 af = scr_frag(scr, kh * 32 + l31, kb * 16 + h * 8);
      accd = __builtin_amdgcn_mfma_f32_32x32x16_f16(af, bf, accd, 0, 0, 0);
    }
#pragma unroll
    for (int j = 0; j < 16; ++j) {
      const int r0 = (j & 3) + 8 * (j >> 2) + 4 * h;
      out[(size_t)(bg0 + kh * 32 + r0) * 64 + scol] = accd[j];
    }
  }
}

extern "C" void kernel_launch(void* const* d_in, const int* in_sizes, int n_in,
                              void* d_out, int out_size, void* d_ws, size_t ws_size,
                              hipStream_t stream) {
  const float* x      = (const float*)d_in[0];
  const float* layer0 = (const float*)d_in[1];
  const float* core1  = (const float*)d_in[2];
  const float* core2  = (const float*)d_in[3];
  const float* last   = (const float*)d_in[4];
  const float* lnw    = (const float*)d_in[5];
  const float* lnb    = (const float*)d_in[6];
  unsigned char* ws   = (unsigned char*)d_ws;
  float* outp         = (float*)d_out;

  tt_prep<<<1036, 512, 0, stream>>>(layer0, core1, core2, last, ws);
  tt_fused<<<512, 512, 0, stream>>>(x, lnw, lnb, ws, outp);
}

// Round 8
// 101.477 us; speedup vs baseline: 1.9061x; 1.8801x over previous
//
#include <hip/hip_runtime.h>
#include <hip/hip_fp16.h>

// B=32768, D=128, L=3, R=64, O=64. fp32 in/out, f16 MFMA compute.
// Round-3 mechanics EXACTLY (staged non-atomic reduce, T buffer, 2-slot
// drain-0 ring, pitch-520 xn12) scaled to TB=128: 256 WGs x 1024 threads
// (16 waves: p/kh/sb/mh). Halves per-CU core L2 stream + LDS DMA writes
// vs TB=64 (each WG streams the full 2MB core set once instead of twice
// per CU). x read exactly once; core chunk LDS reads read-once per parity.
typedef _Float16 f16x8 __attribute__((ext_vector_type(8)));
typedef float f32x16 __attribute__((ext_vector_type(16)));

union H2x4 { f16x8 v; __half2 h2[4]; unsigned u[4]; };
union U1H2 { unsigned u; __half2 h; };

#define TB 128              // batch rows per workgroup (256 WGs = 1/CU)
// LDS layout (bytes)
#define XN0_OFF  0          // xn0 [row<128][256B swz] = 32KB; scr0 at reduce time
#define RING_OFF 32768      // 2 x 16KB core chunk ring; scr1 at reduce time
#define T_OFF    65536      // T buffer [128][64]f16, 128B rows, XOR swz = 16KB
#define XN12_OFF 81920      // xn slices 1,2: [d<128] pitch 520B = 66560B
#define SMEM_BYTES 148480   // 1 WG/CU (<= 163840)
// workspace layout (bytes)
#define WS_CT1   0          // core1 -> [d][s][r] f16, swizzled, 1MB
#define WS_CT2   1048576    // core2 same
#define WS_L0T   2097152    // layer0^T [r][d] f16, 16KB
#define WS_LASTT 2113536    // last^T [o][r] f16, 8KB

#define WAITBAR0() asm volatile("s_waitcnt vmcnt(0)\n\ts_barrier" ::: "memory")

__device__ __forceinline__ void gload_lds16(const void* g, void* l) {
  __builtin_amdgcn_global_load_lds(
      (const __attribute__((address_space(1))) unsigned int*)g,
      (__attribute__((address_space(3))) unsigned int*)l, 16, 0, 0);
}

// stage one 16KB core chunk (2 d's): 1 load/thread at 1024 threads
__device__ __forceinline__ void issue_chunk16(const unsigned char* g,
                                              unsigned char* l, int tid) {
  gload_lds16(g + tid * 16, l + tid * 16);
}

__device__ __forceinline__ unsigned pack_h2(float a, float b) {
  return (unsigned)__half_as_ushort(__float2half(a)) |
         ((unsigned)__half_as_ushort(__float2half(b)) << 16);
}

// 4-way (p x kh) cross-wave reduce, r3 staged scheme (no atomics):
// scr(kh) = 32KB f32 [128][64] regions (scr0 = xn0 region, scr1 = ring),
// p0 writes, p1 adds, p0 combines kh-pair -> T [128][64] f16 swizzled.
__device__ __forceinline__ void reduce_T(unsigned char* smem, f32x16 a0, f32x16 a1,
                                         int p, int kh, int mh, int h, int scol) {
  float* scr = (float*)(smem + (kh ? RING_OFF : XN0_OFF));
  __syncthreads();
  if (p == 0) {
#pragma unroll
    for (int j = 0; j < 16; ++j) {
      const int r0 = (j & 3) + 8 * (j >> 2) + 4 * h;
      const int row = mh * 64 + r0;
      scr[row * 64 + scol] = a0[j];
      scr[(row + 32) * 64 + scol] = a1[j];
    }
  }
  __syncthreads();
  if (p == 1) {
#pragma unroll
    for (int j = 0; j < 16; ++j) {
      const int r0 = (j & 3) + 8 * (j >> 2) + 4 * h;
      const int row = mh * 64 + r0;
      scr[row * 64 + scol] += a0[j];
      scr[(row + 32) * 64 + scol] += a1[j];
    }
  }
  __syncthreads();
  if (p == 0) {  // wave (kh,sb,mh) combines rows mh*64+kh*32.. across kh-pair
    const float* s0 = (const float*)(smem + XN0_OFF);
    const float* s1 = (const float*)(smem + RING_OFF);
#pragma unroll
    for (int j = 0; j < 16; ++j) {
      const int r0 = (j & 3) + 8 * (j >> 2) + 4 * h;
      const int row = mh * 64 + kh * 32 + r0;
      const float vsum = s0[row * 64 + scol] + s1[row * 64 + scol];
      *(__half*)(smem + T_OFF + row * 128 + ((2 * scol) ^ ((row & 7) << 4))) =
          __float2half(vsum);
    }
  }
  __syncthreads();
}

// ---- prep: cast weights to f16 in the layouts the main kernel wants ----
__global__ void __launch_bounds__(512) tt_prep(
    const float* __restrict__ layer0, const float* __restrict__ core1,
    const float* __restrict__ core2, const float* __restrict__ last,
    unsigned char* __restrict__ ws) {
  const int tid = blockIdx.x * 512 + threadIdx.x;
  if (tid < 524288) {                       // ct1/ct2: 2 x 262144 words
    const int which = tid >> 18;
    const int w = tid & 262143;
    const float* core = which ? core2 : core1;
    unsigned char* ct = ws + (which ? WS_CT2 : WS_CT1);
    const int d = w >> 11, rem = w & 2047, s = rem >> 5, j = rem & 31, r = 2 * j;
    const unsigned val = pack_h2(core[r * 8192 + d * 64 + s],
                                 core[(r + 1) * 8192 + d * 64 + s]);
    // byte (2r) within the [s][r] plane XOR-swizzled by ((s&7)<<4)
    *(unsigned*)(ct + d * 8192 + s * 128 + 4 * (j ^ ((s & 7) << 2))) = val;
  } else if (tid < 528384) {                // l0t: 4096 words, [r][d] f16 (256B rows)
    const int w = tid - 524288;
    const int r = w >> 6, j = w & 63, d = 2 * j;
    const unsigned val = pack_h2(layer0[d * 64 + r], layer0[(d + 1) * 64 + r]);
    *(unsigned*)(ws + WS_L0T + r * 256 + 4 * j) = val;
  } else if (tid < 530432) {                // lastT: 2048 words, [o][r] f16 (128B rows)
    const int w = tid - 528384;
    const int o = w >> 5, j = w & 31, r = 2 * j;
    const unsigned val = pack_h2(last[r * 64 + o], last[(r + 1) * 64 + o]);
    *(unsigned*)(ws + WS_LASTT + o * 128 + 4 * j) = val;
  }
}

// ---- fused main kernel: LN + 4-stage tensor-train chain ----
__global__ void __launch_bounds__(1024, 4) tt_fused(
    const float* __restrict__ x, const float* __restrict__ lnw,
    const float* __restrict__ lnb, const unsigned char* __restrict__ ws,
    float* __restrict__ out) {
  __shared__ alignas(16) unsigned char smem[SMEM_BYTES];
  const int tid = threadIdx.x;
  const int wid = tid >> 6;
  const int lane = tid & 63;
  const int l31 = lane & 31;
  const int h = lane >> 5;
  const int p  = wid & 1;           // d-parity within chunk
  const int kh = (wid >> 1) & 1;    // r-half (K-split over r)
  const int sb = (wid >> 2) & 1;    // s-block (32 cols)
  const int mh = (wid >> 3) & 1;    // m-half (64 rows)
  const int bg0 = blockIdx.x * TB;
  const int scol = sb * 32 + l31;   // this lane's B-col
  const int sOff = scol * 128;
  const int swzA = (l31 & 7) << 4;  // == (row&7)<<4 for rows mh*64+mb*32+l31

  // ---------- phase 0: LN; xn0 -> [row][256B swz]; xn1,2 -> XN12 (pitch 520) ----------
  {
    float wv[6], bv[6];
#pragma unroll
    for (int k = 0; k < 6; ++k) { wv[k] = lnw[lane + 64 * k]; bv[k] = lnb[lane + 64 * k]; }
#pragma unroll
    for (int rr = 0; rr < 8; ++rr) {
      const int row = wid * 8 + rr;           // 16 waves x 8 = 128 rows
      const float* xrow = x + (size_t)(bg0 + row) * 384;
      float v[6];
#pragma unroll
      for (int k = 0; k < 6; ++k) v[k] = xrow[lane + 64 * k];
      float s = 0.f, ss = 0.f;
#pragma unroll
      for (int k = 0; k < 6; ++k) { s += v[k]; ss += v[k] * v[k]; }
#pragma unroll
      for (int m = 1; m < 64; m <<= 1) { s += __shfl_xor(s, m); ss += __shfl_xor(ss, m); }
      const float mu = s * (1.f / 384.f);
      const float var = ss * (1.f / 384.f) - mu * mu;
      const float rstd = rsqrtf(var + 1e-5f);
#pragma unroll
      for (int k = 0; k < 6; ++k) {
        const int i = lane + 64 * k;          // i = 3*d + sl
        const int d = i / 3;
        const int sl = i - 3 * d;
        const float xv = (v[k] - mu) * rstd * wv[k] + bv[k];
        if (sl == 0) {
          *(__half*)(smem + XN0_OFF + row * 256 + ((2 * d) ^ ((row & 7) << 4))) =
              __float2half(xv);
        } else {
          *(__half*)(smem + XN12_OFF + d * 520 + 4 * row + 2 * (sl - 1)) =
              __float2half(xv);
        }
      }
    }
  }
  __syncthreads();

  f32x16 acc0, acc1;  // rows mh*64+0..31 / mh*64+32..63 of (kh,sb) partial

  // ---------- stage A: T1 = xn0 @ layer0 (K=128, 4-way (p,kh) K-split) ----------
#pragma unroll
  for (int i = 0; i < 16; ++i) { acc0[i] = 0.f; acc1[i] = 0.f; }
  {
    const unsigned char* l0t = ws + WS_L0T;
#pragma unroll
    for (int kbL = 0; kbL < 2; ++kbL) {
      const int cb = (((p << 1) | kh) * 2 + kbL) * 32 + h * 16;
      f16x8 bf = *(const f16x8*)(l0t + scol * 256 + cb);
      f16x8 a0 = *(const f16x8*)(smem + XN0_OFF + (mh * 64 + l31) * 256 + (cb ^ swzA));
      f16x8 a1 = *(const f16x8*)(smem + XN0_OFF + (mh * 64 + 32 + l31) * 256 + (cb ^ swzA));
      acc0 = __builtin_amdgcn_mfma_f32_32x32x16_f16(a0, bf, acc0, 0, 0, 0);
      acc1 = __builtin_amdgcn_mfma_f32_32x32x16_f16(a1, bf, acc1, 0, 0, 0);
    }
  }
  reduce_T(smem, acc0, acc1, p, kh, mh, h, scol);  // -> T1 (xn0/ring become scr)

  // ---------- stages B,C: T = KR(T, xn_l) @ core_l ----------
  for (int st = 0; st < 2; ++st) {
    const unsigned char* ctg = ws + (st ? WS_CT2 : WS_CT1);

    // prologue: chunk 0 -> ring slot 0 (scr1 dead after reduce_T final sync)
    issue_chunk16(ctg, smem + RING_OFF, tid);

    // T rows (both m-blocks x this wave's r-half K=32) into NAMED packed regs
    H2x4 tp00, tp01, tp10, tp11;   // tp<mb><kbL>
    {
      const int rb0 = kh * 64 + h * 16;
      const int ra = (mh * 64 + l31) * 128;
      const int rb = (mh * 64 + 32 + l31) * 128;
      tp00.v = *(const f16x8*)(smem + T_OFF + ra + (rb0 ^ swzA));
      tp01.v = *(const f16x8*)(smem + T_OFF + ra + ((rb0 + 32) ^ swzA));
      tp10.v = *(const f16x8*)(smem + T_OFF + rb + (rb0 ^ swzA));
      tp11.v = *(const f16x8*)(smem + T_OFF + rb + ((rb0 + 32) ^ swzA));
    }

#pragma unroll
    for (int i = 0; i < 16; ++i) { acc0[i] = 0.f; acc1[i] = 0.f; }

    // ring: chunk cg in slot (cg&1); issue cg+1 into the other slot
#pragma unroll 1
    for (int cg = 0; cg < 64; ++cg) {
      WAITBAR0();   // chunk cg landed (issued >= 1 full iteration ago)
      if (cg < 63)
        issue_chunk16(ctg + (cg + 1) * 16384,
                      smem + RING_OFF + ((cg + 1) & 1) * 16384, tid);
      // compute chunk cg: this wave's d = 2*cg + p
      const unsigned char* bp =
          smem + RING_OFF + (cg & 1) * 16384 + p * 8192 + sOff;
      const unsigned char* xp = smem + XN12_OFF + (2 * cg + p) * 520 +
                                4 * (mh * 64 + l31) + 2 * st;
      const unsigned xv0 = *(const unsigned short*)xp;
      const unsigned xv1 = *(const unsigned short*)(xp + 128);
      U1H2 d0, d1;
      d0.u = xv0 | (xv0 << 16);
      d1.u = xv1 | (xv1 << 16);
      const int rb = kh * 64 + h * 16;
      {  // kbL = 0
        f16x8 bf = *(const f16x8*)(bp + (rb ^ swzA));
        H2x4 af0, af1;
#pragma unroll
        for (int i = 0; i < 4; ++i) {
          af0.h2[i] = __hmul2(tp00.h2[i], d0.h);
          af1.h2[i] = __hmul2(tp10.h2[i], d1.h);
        }
        acc0 = __builtin_amdgcn_mfma_f32_32x32x16_f16(af0.v, bf, acc0, 0, 0, 0);
        acc1 = __builtin_amdgcn_mfma_f32_32x32x16_f16(af1.v, bf, acc1, 0, 0, 0);
      }
      {  // kbL = 1
        f16x8 bf = *(const f16x8*)(bp + ((rb + 32) ^ swzA));
        H2x4 af0, af1;
#pragma unroll
        for (int i = 0; i < 4; ++i) {
          af0.h2[i] = __hmul2(tp01.h2[i], d0.h);
          af1.h2[i] = __hmul2(tp11.h2[i], d1.h);
        }
        acc0 = __builtin_amdgcn_mfma_f32_32x32x16_f16(af0.v, bf, acc0, 0, 0, 0);
        acc1 = __builtin_amdgcn_mfma_f32_32x32x16_f16(af1.v, bf, acc1, 0, 0, 0);
      }
    }
    reduce_T(smem, acc0, acc1, p, kh, mh, h, scol);  // -> T2 then T3
  }

  // ---------- stage D: out = T3 @ last (p==0 waves; rows mh*64+kh*32..) ----------
  if (p == 0) {
    f32x16 accd;
#pragma unroll
    for (int i = 0; i < 16; ++i) accd[i] = 0.f;
    const unsigned char* lastT = ws + WS_LASTT;
    const int rbase = mh * 64 + kh * 32;
#pragma unroll
    for (int kb = 0; kb < 4; ++kb) {
      const int cb = kb * 32 + h * 16;
      f16x8 bf = *(const f16x8*)(lastT + scol * 128 + cb);
      f16x8 af = *(const f16x8*)(smem + T_OFF + (rbase + l31) * 128 + (cb ^ swzA));
      accd = __builtin_amdgcn_mfma_f32_32x32x16_f16(af, bf, accd, 0, 0, 0);
    }
#pragma unroll
    for (int j = 0; j < 16; ++j) {
      const int r0 = (j & 3) + 8 * (j >> 2) + 4 * h;
      out[(size_t)(bg0 + rbase + r0) * 64 + scol] = accd[j];
    }
  }
}

extern "C" void kernel_launch(void* const* d_in, const int* in_sizes, int n_in,
                              void* d_out, int out_size, void* d_ws, size_t ws_size,
                              hipStream_t stream) {
  const float* x      = (const float*)d_in[0];
  const float* layer0 = (const float*)d_in[1];
  const float* core1  = (const float*)d_in[2];
  const float* core2  = (const float*)d_in[3];
  const float* last   = (const float*)d_in[4];
  const float* lnw    = (const float*)d_in[5];
  const float* lnb    = (const float*)d_in[6];
  unsigned char* ws   = (unsigned char*)d_ws;
  float* outp         = (float*)d_out;

  tt_prep<<<1036, 512, 0, stream>>>(layer0, core1, core2, last, ws);
  tt_fused<<<256, 1024, 0, stream>>>(x, lnw, lnb, ws, outp);
}